// Round 1
// baseline (1119.190 us; speedup 1.0000x reference)
//
#include <hip/hip_runtime.h>

// Problem constants (from reference)
#define N_NODESC 50000
#define N_EDGESC 800000
#define DFEAT 64
#define KCOMBO 16
#define EPSF 1e-5

// ws layout (bytes); required ws_size >= ~45 MB
#define WS_DSUM   0                         // 64 double
#define WS_DSQ    512                       // 64 double
#define WS_SCALE  1024                      // 64 float
#define WS_SHIFT  1280                      // 64 float
#define WS_CCOUNT 1536                      // 16 int
#define WS_COFF   1600                      // 17 int
#define WS_CFILL  1728                      // 16 int
#define WS_HA     4096                      // 50000*64 f32 (12.8MB)
#define WS_HB     (4096 + 12800000)
#define WS_AGG    (4096 + 2*12800000)
#define WS_ELIST  (4096 + 3*12800000)       // 800000 int
#define WS_COMBO  (WS_ELIST + 3200000)      // 800000 int

// ---------------- combo classify + count ----------------
__global__ __launch_bounds__(256)
void k_count(const int* __restrict__ src, const int* __restrict__ dst,
             const int* __restrict__ labels, const int* __restrict__ bidx,
             int* __restrict__ combo, int* __restrict__ ccount)
{
    __shared__ int hist[KCOMBO];
    const int tid = threadIdx.x;
    if (tid < KCOMBO) hist[tid] = 0;
    __syncthreads();
    const int e = blockIdx.x * 256 + tid;
    if (e < N_EDGESC) {
        const int s = src[e], d = dst[e];
        const int c = (labels[d] * 2 + labels[s]) * 4 + bidx[e];
        combo[e] = c;
        atomicAdd(&hist[c], 1);
    }
    __syncthreads();
    if (tid < KCOMBO && hist[tid] > 0) atomicAdd(&ccount[tid], hist[tid]);
}

__global__ void k_scan(const int* __restrict__ ccount, int* __restrict__ coff,
                       int* __restrict__ cfill)
{
    if (threadIdx.x == 0) {
        int run = 0;
        for (int k = 0; k < KCOMBO; ++k) {
            coff[k] = run; cfill[k] = run;
            run += ccount[k];
        }
        coff[KCOMBO] = run;
    }
}

__global__ __launch_bounds__(256)
void k_fill(const int* __restrict__ combo, int* __restrict__ cfill,
            int* __restrict__ elist)
{
    __shared__ int hist[KCOMBO], base[KCOMBO];
    const int tid = threadIdx.x;
    if (tid < KCOMBO) hist[tid] = 0;
    __syncthreads();
    const int e = blockIdx.x * 256 + tid;
    int c = 0, rk = 0;
    if (e < N_EDGESC) {
        c = combo[e];
        rk = atomicAdd(&hist[c], 1);
    }
    __syncthreads();
    if (tid < KCOMBO) base[tid] = (hist[tid] > 0) ? atomicAdd(&cfill[tid], hist[tid]) : 0;
    __syncthreads();
    if (e < N_EDGESC) elist[base[c] + rk] = e;
}

// ---------------- h = in @ W + b ; agg = h ----------------
__global__ __launch_bounds__(256)
void k_h(const float* __restrict__ in, const float* __restrict__ W,
         const float* __restrict__ b, float* __restrict__ h,
         float* __restrict__ agg, const int F)
{
    const int t = blockIdx.x * 256 + threadIdx.x;
    if (t >= N_NODESC * 64) return;
    const int n = t >> 6, e = t & 63;
    const float* __restrict__ xr = in + (long)n * F;
    float acc = b[e];
    for (int f = 0; f < F; f += 4) {
        acc += xr[f]     * W[f * 64 + e];
        acc += xr[f + 1] * W[(f + 1) * 64 + e];
        acc += xr[f + 2] * W[(f + 2) * 64 + e];
        acc += xr[f + 3] * W[(f + 3) * 64 + e];
    }
    h[t] = acc;
    agg[t] = acc;
}

// ---------------- per-edge messages, combo-bucketed ----------------
// grid = 1024 blocks; block handles combo = blockIdx & 15.
// LDS: Mt (transposed matrix, 16KB) + per-wave h staging (4x4KB).
__global__ __launch_bounds__(256, 4)
void k_msg(const float* __restrict__ h, float* __restrict__ agg,
           const float* __restrict__ M, const int* __restrict__ elist,
           const int* __restrict__ coff, const int* __restrict__ src,
           const int* __restrict__ dst)
{
    __shared__ float  MtL[64 * 64];          // Mt[f][e] = M[c][e][f]
    __shared__ float4 hbuf[4][16 * 16];      // [wave][f4*16 + j]
    const int tid = threadIdx.x;
    const int c   = blockIdx.x & 15;
    const int bic = blockIdx.x >> 4;         // 0..63 blocks per combo

    const float* __restrict__ Mc = M + c * 4096;
#pragma unroll
    for (int r = 0; r < 16; ++r) {
        const int idx = r * 256 + tid;       // idx = e*64 + f
        MtL[(idx & 63) * 64 + (idx >> 6)] = Mc[idx];
    }
    __syncthreads();

    const int w = tid >> 6, lane = tid & 63;
    const int jj = lane >> 2, q = lane & 3;  // lane covers (edge jj, float4 quad q)
    const int begin = coff[c], end = coff[c + 1];
    const float4* __restrict__ h4 = (const float4*)h;
    const int slot = bic * 4 + w;            // 0..255 wave slots per combo

    for (int gb = begin + slot * 16; gb < end; gb += 256 * 16) {
        const int nv = min(16, end - gb);
        int s = 0, d = 0;
        if (lane < nv) {
            const int eid = elist[gb + lane];
            s = src[eid];
            d = dst[eid];
        }
        const int  sj = __shfl(s, jj);
        const bool jv = (jj < nv);
        // stage h rows: hbuf[w][f4][j] = h[src_j][4*f4 .. 4*f4+3]
#pragma unroll
        for (int r = 0; r < 4; ++r) {
            float4 v = make_float4(0.f, 0.f, 0.f, 0.f);
            if (jv) v = h4[(long)sj * 16 + q + 4 * r];
            hbuf[w][(q + 4 * r) * 16 + jj] = v;
        }
        asm volatile("s_waitcnt lgkmcnt(0)" ::: "memory");

        float acc[16];
#pragma unroll
        for (int j = 0; j < 16; ++j) acc[j] = 0.f;

#pragma unroll 4
        for (int f4 = 0; f4 < 16; ++f4) {
            const float m0 = MtL[(4 * f4 + 0) * 64 + lane];
            const float m1 = MtL[(4 * f4 + 1) * 64 + lane];
            const float m2 = MtL[(4 * f4 + 2) * 64 + lane];
            const float m3 = MtL[(4 * f4 + 3) * 64 + lane];
#pragma unroll
            for (int j = 0; j < 16; ++j) {
                const float4 hv = hbuf[w][f4 * 16 + j];
                acc[j] += m0 * hv.x + m1 * hv.y + m2 * hv.z + m3 * hv.w;
            }
        }
        asm volatile("s_waitcnt lgkmcnt(0)" ::: "memory");

#pragma unroll
        for (int j = 0; j < 16; ++j) {
            if (j < nv) {
                const int dj = __shfl(d, j);
                atomicAdd(&agg[(long)dj * 64 + lane], acc[j]);
            }
        }
    }
}

// ---------------- feature-wise stats over nodes ----------------
__global__ __launch_bounds__(256)
void k_stats(const float* __restrict__ agg, double* __restrict__ dsum,
             double* __restrict__ dsq)
{
    __shared__ float l1[256], l2[256];
    const int e = threadIdx.x & 63, r = threadIdx.x >> 6;
    const int n0 = blockIdx.x * 196;
    const int n1 = min(n0 + 196, N_NODESC);
    float s1 = 0.f, s2 = 0.f;
    for (int n = n0 + r; n < n1; n += 4) {
        const float v = agg[(long)n * 64 + e];
        s1 += v; s2 += v * v;
    }
    l1[threadIdx.x] = s1; l2[threadIdx.x] = s2;
    __syncthreads();
    if (r == 0) {
        s1 = l1[e] + l1[64 + e] + l1[128 + e] + l1[192 + e];
        s2 = l2[e] + l2[64 + e] + l2[128 + e] + l2[192 + e];
        atomicAdd(&dsum[e], (double)s1);
        atomicAdd(&dsq[e], (double)s2);
    }
}

__global__ void k_norm(const double* __restrict__ dsum, const double* __restrict__ dsq,
                       const float* __restrict__ g, const float* __restrict__ be,
                       float* __restrict__ scale, float* __restrict__ shift)
{
    const int e = threadIdx.x;
    if (e >= 64) return;
    const double mu  = dsum[e] / (double)N_NODESC;
    const double var = dsq[e] / (double)N_NODESC - mu * mu;
    const double sc  = (double)g[e] / sqrt(var + EPSF);
    scale[e] = (float)sc;
    shift[e] = (float)((double)be[e] - mu * sc);
}

__global__ __launch_bounds__(256)
void k_apply(const float* __restrict__ agg, const float* __restrict__ scale,
             const float* __restrict__ shift, float* __restrict__ hout)
{
    const int t = blockIdx.x * 256 + threadIdx.x;
    if (t >= N_NODESC * 64) return;
    const int e = t & 63;
    const float v = agg[t] * scale[e] + shift[e];
    hout[t] = fmaxf(v, 0.f);
}

// ---------------- final projection ----------------
__global__ __launch_bounds__(256)
void k_out(const float* __restrict__ hA, const float* __restrict__ resW,
           const float* __restrict__ resb, float* __restrict__ out)
{
    const int n = blockIdx.x * 256 + threadIdx.x;
    if (n >= N_NODESC) return;
    float a0 = resb[0], a1 = resb[1];
    const float* __restrict__ hr = hA + (long)n * 64;
#pragma unroll 8
    for (int e = 0; e < 64; ++e) {
        const float v = hr[e];
        a0 += v * resW[2 * e];
        a1 += v * resW[2 * e + 1];
    }
    out[2 * n] = a0;
    out[2 * n + 1] = a1;
}

extern "C" void kernel_launch(void* const* d_in, const int* in_sizes, int n_in,
                              void* d_out, int out_size, void* d_ws, size_t ws_size,
                              hipStream_t stream)
{
    const float* x      = (const float*)d_in[0];
    const float* M      = (const float*)d_in[1];   // (16,64,64)
    const int*   src    = (const int*)d_in[2];
    const int*   dst    = (const int*)d_in[3];
    const int*   labels = (const int*)d_in[4];
    const int*   bidx   = (const int*)d_in[5];
    const float* resW   = (const float*)d_in[18];
    const float* resb   = (const float*)d_in[19];
    float* out = (float*)d_out;

    char* ws = (char*)d_ws;
    double* dsum  = (double*)(ws + WS_DSUM);
    double* dsq   = (double*)(ws + WS_DSQ);
    float*  scale = (float*)(ws + WS_SCALE);
    float*  shift = (float*)(ws + WS_SHIFT);
    int*    ccount= (int*)(ws + WS_CCOUNT);
    int*    coff  = (int*)(ws + WS_COFF);
    int*    cfill = (int*)(ws + WS_CFILL);
    float*  hA    = (float*)(ws + WS_HA);
    float*  hB    = (float*)(ws + WS_HB);
    float*  agg   = (float*)(ws + WS_AGG);
    int*    elist = (int*)(ws + WS_ELIST);
    int*    combo = (int*)(ws + WS_COMBO);

    const int EB = (N_EDGESC + 255) / 256;        // 3125
    const int NB64 = (N_NODESC * 64 + 255) / 256; // 12500
    const int NBn = (N_NODESC + 255) / 256;       // 196

    // edge bucketing by combo (labels/bidx constant across layers)
    hipMemsetAsync(ccount, 0, KCOMBO * sizeof(int), stream);
    k_count<<<EB, 256, 0, stream>>>(src, dst, labels, bidx, combo, ccount);
    k_scan<<<1, 64, 0, stream>>>(ccount, coff, cfill);
    k_fill<<<EB, 256, 0, stream>>>(combo, cfill, elist);

    for (int l = 0; l < 3; ++l) {
        const float* W  = (const float*)d_in[6 + 4 * l];
        const float* b  = (const float*)d_in[7 + 4 * l];
        const float* g  = (const float*)d_in[8 + 4 * l];
        const float* be = (const float*)d_in[9 + 4 * l];
        const float* in = (l == 0) ? x : hA;
        const int F = (l == 0) ? 128 : 64;

        k_h<<<NB64, 256, 0, stream>>>(in, W, b, hB, agg, F);
        k_msg<<<1024, 256, 0, stream>>>(hB, agg, M, elist, coff, src, dst);
        hipMemsetAsync(dsum, 0, 2 * 64 * sizeof(double), stream);
        k_stats<<<256, 256, 0, stream>>>(agg, dsum, dsq);
        k_norm<<<1, 64, 0, stream>>>(dsum, dsq, g, be, scale, shift);
        k_apply<<<NB64, 256, 0, stream>>>(agg, scale, shift, hA);
    }
    k_out<<<NBn, 256, 0, stream>>>(hA, resW, resb, out);
    (void)in_sizes; (void)n_in; (void)out_size; (void)ws_size;
}